// Round 10
// baseline (24.649 us; speedup 1.0000x reference)
//
#include <hip/hip_runtime.h>
#include <cstddef>

// RoIPool: features (B=2, C=256, H=50, W=50) f32, rois (R,4) f32, roi_indices (R,) int
// out (R, C, 7, 7) f32.
// Reference quirk preserved: h-bins from x coords (ri[:,0], ri[:,2]), w-bins from y.
//
// Single fused kernel, ONE barrier. Block = (slice of 16 ch, roi), 256 thr.
// Stage whole ROI window (<=19 rows x 22 cols x 16 ch = 27.3 KB LDS,
// 5 blocks/CU) as flat float2 segments: all 256 threads, up to 14 independent
// 8B-aligned dwordx2 loads each (row stride 200 B even + y1&~1 base => always
// 8B aligned). One __syncthreads. Then thread = (channel, bin-strip) computes
// dup-clamped 4x4 bin maxima from LDS (channel stride 437 odd => conflict-free)
// and writes out directly (block covers contiguous 3136 B chunk of out).
//
// Distribution-proven bounds: Lh,Lw in [4,19], x1,y1>=0, x2,y2<=49 -> fast
// path always taken; guarded generic global-read fallback kept for safety.

namespace {
constexpr int OUTP = 7;
constexpr int CC = 256;
constexpr int HH = 50;
constexpr int WW = 50;
constexpr int HWSZ = HH * WW;
constexpr int CSPLIT = 16;
constexpr int CPS = CC / CSPLIT;            // 16 channels per slice
constexpr float NEGV = -3e38f;
constexpr int LMAX = 19;                    // max Lh / Lw on fast path
constexpr int JSEG = 11;                    // float2 segments per row (22 cols)
constexpr int RSTR = 23;                    // LDS row stride (22 + 1 pad, odd)
constexpr int CSTR = LMAX * RSTR;           // 437 floats/channel, odd
constexpr int NSEG_MAX = CPS * LMAX * JSEG; // 3344
constexpr int KITER = (NSEG_MAX + 255) / 256;  // 14
typedef float vf2 __attribute__((ext_vector_type(2)));  // 8B aligned
}  // namespace

__global__ __launch_bounds__(256) void roipool_fused(
    const float* __restrict__ feat, const float* __restrict__ rois,
    const int* __restrict__ ridx, float* __restrict__ out) {
    __shared__ float buf[CPS * CSTR];  // 27968 B

    const int s = blockIdx.x;  // linear id % 16 == s -> slice pinned to XCD s%8
    const int r = blockIdx.y;
    const int tid = threadIdx.x;

    const float4 rv = reinterpret_cast<const float4*>(rois)[r];
    int x1 = (int)(rv.x * 0.0625f);
    int y1 = (int)(rv.y * 0.0625f);
    int x2 = (int)(rv.z * 0.0625f);
    int y2 = (int)(rv.w * 0.0625f);
    int b = ridx[r];
    x1 = __builtin_amdgcn_readfirstlane(x1);
    y1 = __builtin_amdgcn_readfirstlane(y1);
    x2 = __builtin_amdgcn_readfirstlane(x2);
    y2 = __builtin_amdgcn_readfirstlane(y2);
    b = __builtin_amdgcn_readfirstlane(b);

    const int Lh = x2 - x1;
    const int Lw = y2 - y1;

    const float* fb = feat + (size_t)(b * CC + s * CPS) * HWSZ;
    float* obase = out + (size_t)(r * CC + s * CPS) * (OUTP * OUTP);

    const bool fast = (Lh >= 1 && Lh <= LMAX && Lw >= 1 && Lw <= LMAX &&
                       x1 >= 0 && y1 >= 0 && x2 < HH && y2 < WW);

    if (fast) {  // block-uniform branch
        const int y1a = y1 & ~1;   // float2-aligned col base (row stride even)
        const int shift = y1 & 1;  // compute-phase col offset in LDS
        const int nseg = CPS * JSEG * Lh;
        const float* gb = fb + (size_t)x1 * WW + y1a;

        // Staged cols may spill into the next image row: in-bounds (last
        // staged row = x2-1 <= 48) and compute never reads past shift+Lw.
#pragma unroll
        for (int k = 0; k < KITER; ++k) {
            const int seg = tid + k * 256;
            if (seg < nseg) {  // independent predicated loads: full MLP
                const int c = seg & (CPS - 1);
                const int rj = seg >> 4;
                const int j = rj % JSEG;    // const-divisor -> magic mul
                const int row = rj / JSEG;
                const vf2 v = *reinterpret_cast<const vf2*>(
                    gb + (size_t)c * HWSZ + row * WW + j * 2);
                float* q = buf + c * CSTR + row * RSTR + j * 2;
                q[0] = v.x;
                q[1] = v.y;
            }
        }
        __syncthreads();

        // Compute: thread = (cc in 0..15, qq in 0..15); bins qq + 16k.
        const int cc = tid & (CPS - 1);
        const int qq = tid >> 4;
        const float* cb = buf + cc * CSTR + shift;
        float* ob = obase + (size_t)cc * (OUTP * OUTP);

#pragma unroll
        for (int k = 0; k < 4; ++k) {
            const int bin = qq + k * 16;
            if (bin < 49) {
                const int ph = bin / OUTP;
                const int pw = bin - ph * OUTP;
                const int h0 = (ph * Lh) / OUTP;
                const int nh = ((ph + 1) * Lh + OUTP - 1) / OUTP - h0;  // 1..4
                const int w0 = (pw * Lw) / OUTP;
                const int nw = ((pw + 1) * Lw + OUTP - 1) / OUTP - w0;  // 1..4
                const float* wb = cb + h0 * RSTR + w0;
                float m = NEGV;
#pragma unroll
                for (int i = 0; i < 4; ++i) {
                    // dup-clamp: out-of-window rows/cols re-read in-window data
                    const int ro = (i < nh ? i : nh - 1) * RSTR;
#pragma unroll
                    for (int jj = 0; jj < 4; ++jj) {
                        const int co = (jj < nw ? jj : nw - 1);
                        m = fmaxf(m, wb[ro + co]);
                    }
                }
                __builtin_nontemporal_store(m, ob + bin);
            }
        }
    } else {
        // Generic fallback: direct global reads (never taken for this input
        // distribution). Empty windows -> NEGV, matching the reference.
        const int cc = tid & (CPS - 1);
        const int qq = tid >> 4;
        const float* cb = fb + (size_t)cc * HWSZ;
        float* ob = obase + (size_t)cc * (OUTP * OUTP);

        for (int k = 0; k < 4; ++k) {
            const int bin = qq + k * 16;
            if (bin < 49) {
                const int ph = bin / OUTP;
                const int pw = bin - ph * OUTP;
                int hs = x1 + (ph * Lh) / OUTP;
                int he = x1 + ((ph + 1) * Lh + OUTP - 1) / OUTP;
                int ws = y1 + (pw * Lw) / OUTP;
                int we = y1 + ((pw + 1) * Lw + OUTP - 1) / OUTP;
                hs = hs < 0 ? 0 : hs;
                he = he > HH ? HH : he;
                ws = ws < 0 ? 0 : ws;
                we = we > WW ? WW : we;
                float m = NEGV;
                for (int h = hs; h < he; ++h) {
                    for (int w = ws; w < we; ++w) {
                        m = fmaxf(m, cb[h * WW + w]);
                    }
                }
                ob[bin] = m;
            }
        }
    }
}

extern "C" void kernel_launch(void* const* d_in, const int* in_sizes, int n_in,
                              void* d_out, int out_size, void* d_ws, size_t ws_size,
                              hipStream_t stream) {
    const float* features = (const float*)d_in[0];
    const float* rois = (const float*)d_in[1];
    const int* ridx = (const int*)d_in[2];
    float* out = (float*)d_out;
    const int R = in_sizes[1] / 4;

    roipool_fused<<<dim3(CSPLIT, R), 256, 0, stream>>>(features, rois, ridx, out);
}